// Round 1
// baseline (1534.613 us; speedup 1.0000x reference)
//
#include <hip/hip_runtime.h>

#define B_  32
#define N_  576
#define C_  768
#define H_  12
#define HD_ 64
#define M_  (B_*N_)    // 18432
#define C3_ (3*C_)     // 2304

// ---------------------------------------------------------------------------
// GEMM: Cm = A @ W^T + bias
//   A: (M,K) row-major, W: (Nout,K) row-major, Cm: (M,Nout) row-major
// 128x128 tile, K-tile 8, 256 threads, 8x8 outputs/thread.
// ---------------------------------------------------------------------------
__global__ __launch_bounds__(256)
void gemm_f32(const float* __restrict__ A, const float* __restrict__ W,
              const float* __restrict__ bias, float* __restrict__ Cm,
              int M, int Nout, int K) {
  __shared__ float As[8][128];
  __shared__ float Bs[8][128];
  const int tid = threadIdx.x;
  const int tx = tid & 15;   // output col group
  const int ty = tid >> 4;   // output row group
  const int m0 = blockIdx.y * 128;
  const int n0 = blockIdx.x * 128;
  const int lr = tid >> 1;          // loader row 0..127
  const int lc = (tid & 1) << 2;    // loader k-offset 0 or 4
  const float* Ap = A + (size_t)(m0 + lr) * K + lc;
  const float* Wp = W + (size_t)(n0 + lr) * K + lc;

  float acc[8][8];
#pragma unroll
  for (int i = 0; i < 8; i++)
#pragma unroll
    for (int j = 0; j < 8; j++) acc[i][j] = 0.f;

  for (int k0 = 0; k0 < K; k0 += 8) {
    const float4 av = *(const float4*)(Ap + k0);
    const float4 wv = *(const float4*)(Wp + k0);
    __syncthreads();   // previous iteration's reads done before overwrite
    As[lc+0][lr] = av.x; As[lc+1][lr] = av.y; As[lc+2][lr] = av.z; As[lc+3][lr] = av.w;
    Bs[lc+0][lr] = wv.x; Bs[lc+1][lr] = wv.y; Bs[lc+2][lr] = wv.z; Bs[lc+3][lr] = wv.w;
    __syncthreads();
#pragma unroll
    for (int kk = 0; kk < 8; ++kk) {
      const float4 a0 = *(const float4*)&As[kk][(ty<<2)];
      const float4 a1 = *(const float4*)&As[kk][(ty<<2) + 64];
      const float4 b0 = *(const float4*)&Bs[kk][(tx<<2)];
      const float4 b1 = *(const float4*)&Bs[kk][(tx<<2) + 64];
      const float a[8] = {a0.x,a0.y,a0.z,a0.w, a1.x,a1.y,a1.z,a1.w};
      const float b[8] = {b0.x,b0.y,b0.z,b0.w, b1.x,b1.y,b1.z,b1.w};
#pragma unroll
      for (int i = 0; i < 8; i++)
#pragma unroll
        for (int j = 0; j < 8; j++) acc[i][j] = fmaf(a[i], b[j], acc[i][j]);
    }
  }

  float bcol[8];
#pragma unroll
  for (int j = 0; j < 8; j++) bcol[j] = bias[n0 + (tx<<2) + (j&3) + ((j>>2)<<6)];
#pragma unroll
  for (int i = 0; i < 8; i++) {
    const int ro = m0 + (ty<<2) + (i&3) + ((i>>2)<<6);
    float* cp = Cm + (size_t)ro * Nout + n0 + (tx<<2);
    float4 r0 = {acc[i][0]+bcol[0], acc[i][1]+bcol[1], acc[i][2]+bcol[2], acc[i][3]+bcol[3]};
    float4 r1 = {acc[i][4]+bcol[4], acc[i][5]+bcol[5], acc[i][6]+bcol[6], acc[i][7]+bcol[7]};
    *(float4*)cp        = r0;
    *(float4*)(cp + 64) = r1;
  }
}

// ---------------------------------------------------------------------------
// Flash-style block-causal attention for one (b,h) x 64-query tile.
// qkv: (B*N, 3C) row-major from the QKV GEMM. aout: (B*N, C).
// Ownership: thread (tx,ty) owns rows {ty+16i}, cols/dims {tx+16j} so every
// LDS b128 read lands on <=2-way bank conflicts (free).
// ---------------------------------------------------------------------------
__global__ __launch_bounds__(256)
void attn_f32(const float* __restrict__ qkv, float* __restrict__ aout) {
  __shared__ float qs[64][68];
  __shared__ float ksps[64][68];   // k-tile, then reused as P
  __shared__ float vst[64][68];    // v-tile transposed: [dim][key]
  __shared__ int   bi_s[N_];
  __shared__ int   tmin[9], tmax[9];
  __shared__ int   qmax_s, qmin_s;

  const int tid = threadIdx.x;
  const int tx  = tid & 15;
  const int ty  = tid >> 4;
  const int bh  = blockIdx.x;
  const int b   = bh / H_;
  const int h   = bh % H_;
  const int q0  = blockIdx.y << 6;

  for (int p = tid; p < N_; p += 256)
    bi_s[p] = (p / 96) * 6 + ((p % 24) >> 2);
  __syncthreads();
  if (tid < 9) {
    int mn = 1 << 30, mx = -1;
    for (int i = 0; i < 64; i++) { int v = bi_s[(tid<<6)+i]; mn = min(mn,v); mx = max(mx,v); }
    tmin[tid] = mn; tmax[tid] = mx;
  }
  if (tid == 9) {
    int mn = 1 << 30, mx = -1;
    for (int i = 0; i < 64; i++) { int v = bi_s[q0+i]; mn = min(mn,v); mx = max(mx,v); }
    qmin_s = mn; qmax_s = mx;
  }
  { // load q tile (64 rows x 64 dims)
    const int row = tid >> 2;
    const int dc  = (tid & 3) << 4;
    const float* src = qkv + (size_t)(b*N_ + q0 + row) * C3_ + h*HD_ + dc;
    float4* dst = (float4*)&qs[row][dc];
#pragma unroll
    for (int u = 0; u < 4; u++) dst[u] = ((const float4*)src)[u];
  }
  __syncthreads();

  int bi_q[4];
#pragma unroll
  for (int i = 0; i < 4; i++) bi_q[i] = bi_s[q0 + ty + (i<<4)];

  float o[4][4], mrun[4], lrun[4];
#pragma unroll
  for (int i = 0; i < 4; i++) {
    mrun[i] = -1e30f; lrun[i] = 0.f;
#pragma unroll
    for (int j = 0; j < 4; j++) o[i][j] = 0.f;
  }

  for (int kt = 0; kt < 9; ++kt) {
    if (tmin[kt] > qmax_s) continue;            // whole key tile in the future
    const bool nomask = (tmax[kt] <= qmin_s);   // whole key tile visible
    __syncthreads();                            // prev PV reads done
    { // load k,v tile
      const int row = tid >> 2;
      const int dc  = (tid & 3) << 4;
      const float* kp = qkv + (size_t)(b*N_ + (kt<<6) + row) * C3_ + C_ + h*HD_ + dc;
      const float* vp = kp + C_;
      float4 k4[4], v4[4];
#pragma unroll
      for (int u = 0; u < 4; u++) { k4[u] = ((const float4*)kp)[u]; v4[u] = ((const float4*)vp)[u]; }
      float4* kd = (float4*)&ksps[row][dc];
#pragma unroll
      for (int u = 0; u < 4; u++) kd[u] = k4[u];
      const float vv[16] = {v4[0].x,v4[0].y,v4[0].z,v4[0].w, v4[1].x,v4[1].y,v4[1].z,v4[1].w,
                            v4[2].x,v4[2].y,v4[2].z,v4[2].w, v4[3].x,v4[3].y,v4[3].z,v4[3].w};
#pragma unroll
      for (int u = 0; u < 16; u++) vst[dc+u][row] = vv[u];
    }
    __syncthreads();

    // S = q @ k^T
    float s[4][4];
#pragma unroll
    for (int i = 0; i < 4; i++)
#pragma unroll
      for (int j = 0; j < 4; j++) s[i][j] = 0.f;
#pragma unroll
    for (int d4 = 0; d4 < 16; ++d4) {
      float4 aa[4], bb[4];
#pragma unroll
      for (int i = 0; i < 4; i++) aa[i] = *(const float4*)&qs[ty + (i<<4)][d4<<2];
#pragma unroll
      for (int j = 0; j < 4; j++) bb[j] = *(const float4*)&ksps[tx + (j<<4)][d4<<2];
#pragma unroll
      for (int i = 0; i < 4; i++)
#pragma unroll
        for (int j = 0; j < 4; j++)
          s[i][j] = fmaf(aa[i].x, bb[j].x, fmaf(aa[i].y, bb[j].y,
                    fmaf(aa[i].z, bb[j].z, fmaf(aa[i].w, bb[j].w, s[i][j]))));
    }

    int bi_k[4];
#pragma unroll
    for (int j = 0; j < 4; j++) bi_k[j] = bi_s[(kt<<6) + tx + (j<<4)];
#pragma unroll
    for (int i = 0; i < 4; i++)
#pragma unroll
      for (int j = 0; j < 4; j++) {
        float v = s[i][j] * 0.125f;
        if (!nomask && (bi_k[j] > bi_q[i])) v = -1e30f;
        s[i][j] = v;
      }

    // online softmax (rows live in 16 consecutive lanes -> xor-shuffle 1,2,4,8)
#pragma unroll
    for (int i = 0; i < 4; i++) {
      float rm = fmaxf(fmaxf(s[i][0], s[i][1]), fmaxf(s[i][2], s[i][3]));
      rm = fmaxf(rm, __shfl_xor(rm, 1));
      rm = fmaxf(rm, __shfl_xor(rm, 2));
      rm = fmaxf(rm, __shfl_xor(rm, 4));
      rm = fmaxf(rm, __shfl_xor(rm, 8));
      const float mnew  = fmaxf(mrun[i], rm);
      const float alpha = __expf(mrun[i] - mnew);
      float rs = 0.f;
#pragma unroll
      for (int j = 0; j < 4; j++) { const float p = __expf(s[i][j] - mnew); s[i][j] = p; rs += p; }
      rs += __shfl_xor(rs, 1);
      rs += __shfl_xor(rs, 2);
      rs += __shfl_xor(rs, 4);
      rs += __shfl_xor(rs, 8);
      lrun[i] = lrun[i] * alpha + rs;
      mrun[i] = mnew;
#pragma unroll
      for (int j = 0; j < 4; j++) o[i][j] *= alpha;
    }

    __syncthreads();        // everyone done reading k from ksps
#pragma unroll
    for (int i = 0; i < 4; i++)
#pragma unroll
      for (int j = 0; j < 4; j++) ksps[ty + (i<<4)][tx + (j<<4)] = s[i][j];
    __syncthreads();

    // O += P @ V
#pragma unroll
    for (int k4 = 0; k4 < 16; ++k4) {
      float4 pa[4], vb[4];
#pragma unroll
      for (int i = 0; i < 4; i++) pa[i] = *(const float4*)&ksps[ty + (i<<4)][k4<<2];
#pragma unroll
      for (int j = 0; j < 4; j++) vb[j] = *(const float4*)&vst[tx + (j<<4)][k4<<2];
#pragma unroll
      for (int i = 0; i < 4; i++)
#pragma unroll
        for (int j = 0; j < 4; j++)
          o[i][j] = fmaf(pa[i].x, vb[j].x, fmaf(pa[i].y, vb[j].y,
                    fmaf(pa[i].z, vb[j].z, fmaf(pa[i].w, vb[j].w, o[i][j]))));
    }
  }

  // normalize + write (B*N, C)
#pragma unroll
  for (int i = 0; i < 4; i++) {
    const float inv = 1.f / lrun[i];
    float* op = aout + (size_t)(b*N_ + q0 + ty + (i<<4)) * C_ + h*HD_ + tx;
#pragma unroll
    for (int j = 0; j < 4; j++) op[j<<4] = o[i][j] * inv;
  }
}

// ---------------------------------------------------------------------------
extern "C" void kernel_launch(void* const* d_in, const int* in_sizes, int n_in,
                              void* d_out, int out_size, void* d_ws, size_t ws_size,
                              hipStream_t stream) {
  const float* x      = (const float*)d_in[0];
  const float* qkv_w  = (const float*)d_in[1];   // (2304, 768)
  const float* qkv_b  = (const float*)d_in[2];   // (2304)
  const float* proj_w = (const float*)d_in[3];   // (768, 768)
  const float* proj_b = (const float*)d_in[4];   // (768)
  float* out = (float*)d_out;                    // (18432, 768)

  // workspace: qkv (M x 3C) then attn_out (M x C)  => ~219 MB
  float* qkv      = (float*)d_ws;
  float* attn_out = qkv + (size_t)M_ * C3_;

  // 1) qkv = x @ qkv_w^T + qkv_b   (M=18432, Nout=2304, K=768)
  gemm_f32<<<dim3(C3_/128, M_/128), 256, 0, stream>>>(x, qkv_w, qkv_b, qkv, M_, C3_, C_);

  // 2) block-causal attention -> attn_out (M x C)
  attn_f32<<<dim3(B_*H_, N_/64), 256, 0, stream>>>(qkv, attn_out);

  // 3) out = attn_out @ proj_w^T + proj_b  (M=18432, Nout=768, K=768)
  gemm_f32<<<dim3(C_/128, M_/128), 256, 0, stream>>>(attn_out, proj_w, proj_b, out, M_, C_, C_);
}

// Round 2
// 847.276 us; speedup vs baseline: 1.8112x; 1.8112x over previous
//
#include <hip/hip_runtime.h>
#include <stdint.h>

#define B_  32
#define N_  576
#define C_  768
#define H_  12
#define HD_ 64
#define M_  (B_*N_)    // 18432
#define C3_ (3*C_)     // 2304
#define K_  768

typedef __attribute__((ext_vector_type(8))) short short8;
typedef __attribute__((ext_vector_type(4))) float f32x4;

__device__ __forceinline__ uint  f2u(float x){ return __float_as_uint(x); }
__device__ __forceinline__ float u2f(uint x){ return __uint_as_float(x); }

// split two f32 into packed (bf16 hi pair, bf16 lo pair); truncation split:
// hi = top16(a) exactly, lo = bf16(a - hi): combined rel error <= 2^-16.
__device__ __forceinline__ void split2(float a, float b, uint& hw, uint& lw) {
  uint b0 = f2u(a), b1 = f2u(b);
  uint t0 = b0 & 0xffff0000u, t1 = b1 & 0xffff0000u;
  hw = (b0 >> 16) | t1;
  lw = (f2u(a - u2f(t0)) >> 16) | (f2u(b - u2f(t1)) & 0xffff0000u);
}

// reconstruct 8 f32 from packed hi/lo bf16 planes
__device__ __forceinline__ void unpack8(uint4 hv, uint4 lv, float* f) {
  f[0] = u2f(hv.x << 16)        + u2f(lv.x << 16);
  f[1] = u2f(hv.x & 0xffff0000u) + u2f(lv.x & 0xffff0000u);
  f[2] = u2f(hv.y << 16)        + u2f(lv.y << 16);
  f[3] = u2f(hv.y & 0xffff0000u) + u2f(lv.y & 0xffff0000u);
  f[4] = u2f(hv.z << 16)        + u2f(lv.z << 16);
  f[5] = u2f(hv.z & 0xffff0000u) + u2f(lv.z & 0xffff0000u);
  f[6] = u2f(hv.w << 16)        + u2f(lv.w << 16);
  f[7] = u2f(hv.w & 0xffff0000u) + u2f(lv.w & 0xffff0000u);
}

// async global->LDS 16B DMA (CK-style addrspace cast)
__device__ __forceinline__ void gload16(const ushort* g, ushort* l) {
  auto gp = (const __attribute__((address_space(1))) uint*)(g);
  auto lp = reinterpret_cast<__attribute__((address_space(3))) uint*>(
              reinterpret_cast<uintptr_t>(l));
  __builtin_amdgcn_global_load_lds(gp, lp, 16, 0, 0);
}

// elementwise f32 -> (hi,lo) bf16 planes
__global__ __launch_bounds__(256)
void split_f32(const float* __restrict__ src, ushort* __restrict__ hi,
               ushort* __restrict__ lo, int n4) {
  int i = blockIdx.x * 256 + threadIdx.x;
  if (i >= n4) return;
  float4 a = ((const float4*)src)[i];
  uint h0, l0, h1, l1;
  split2(a.x, a.y, h0, l0); split2(a.z, a.w, h1, l1);
  ((uint2*)hi)[i] = make_uint2(h0, h1);
  ((uint2*)lo)[i] = make_uint2(l0, l1);
}

// ---------------------------------------------------------------------------
// Split-bf16 MFMA GEMM: C = A @ W^T + bias  (A:(M,K), W:(Nout,K) row-major)
// 128x128 tile, BK=32, 4 waves x 4x4 tiles of 16x16x32 bf16 MFMA, 3 products.
// LDS chunk swizzle: logical (row, c) chunk (16B) stored at slot
//   row*4 + (c ^ ((row>>1)&3))  -> conflict-free ds_read_b128 frag reads.
// ---------------------------------------------------------------------------
template<bool AF32, bool OUTSPLIT>
__global__ __launch_bounds__(256)
void gemm_mfma(const float* __restrict__ Af, const ushort* __restrict__ Ah,
               const ushort* __restrict__ Al, const ushort* __restrict__ Bh,
               const ushort* __restrict__ Bl, const float* __restrict__ bias,
               float* __restrict__ Cf, ushort* __restrict__ Ch,
               ushort* __restrict__ Cl, int Nout) {
  __shared__ ushort AHs[128*32], ALs[128*32], BHs[128*32], BLs[128*32];

  const int tid  = threadIdx.x;
  const int lane = tid & 63, wave = tid >> 6;
  const int wrow = (wave >> 1) << 6, wcol = (wave & 1) << 6;
  const int m0 = blockIdx.y << 7, n0 = blockIdx.x << 7;

  // fragment read slots (constant across k-chunks)
  int aslot[4], bslot[4];
#pragma unroll
  for (int i = 0; i < 4; i++) {
    int r = wrow + (i << 4) + (lane & 15);
    aslot[i] = (r << 2) + ((lane >> 4) ^ ((r >> 1) & 3));
  }
#pragma unroll
  for (int j = 0; j < 4; j++) {
    int r = wcol + (j << 4) + (lane & 15);
    bslot[j] = (r << 2) + ((lane >> 4) ^ ((r >> 1) & 3));
  }

  // B staging (DMA): per wave 2 parts x 1KB per plane
  int blds[2]; const ushort *bsh[2], *bsl[2];
#pragma unroll
  for (int p = 0; p < 2; p++) {
    int bs = ((wave << 1) + p) << 6;
    int s = bs + lane, row = s >> 2, c = (s & 3) ^ ((row >> 1) & 3);
    blds[p] = bs << 3;
    bsh[p] = Bh + (size_t)(n0 + row) * K_ + (c << 3);
    bsl[p] = Bl + (size_t)(n0 + row) * K_ + (c << 3);
  }

  // A staging
  const float* afp[2]; int adslot[2];
  int alds[2]; const ushort *ash[2], *asl_[2];
#pragma unroll
  for (int u = 0; u < 2; u++) {
    if (AF32) {
      int t2 = tid + (u << 8), ar = t2 >> 2, ac = t2 & 3;
      afp[u] = Af + (size_t)(m0 + ar) * K_ + (ac << 3);
      adslot[u] = (ar << 2) + (ac ^ ((ar >> 1) & 3));
    } else {
      int bs = ((wave << 1) + u) << 6;
      int s = bs + lane, row = s >> 2, c = (s & 3) ^ ((row >> 1) & 3);
      alds[u] = bs << 3;
      ash[u]  = Ah + (size_t)(m0 + row) * K_ + (c << 3);
      asl_[u] = Al + (size_t)(m0 + row) * K_ + (c << 3);
    }
  }

  f32x4 acc[4][4];
#pragma unroll
  for (int i = 0; i < 4; i++)
#pragma unroll
    for (int j = 0; j < 4; j++) acc[i][j] = (f32x4)0.f;

  for (int k0 = 0; k0 < K_; k0 += 32) {
    __syncthreads();   // prev frag reads done before overwrite
#pragma unroll
    for (int p = 0; p < 2; p++) {
      gload16(bsh[p] + k0, &BHs[blds[p]]);
      gload16(bsl[p] + k0, &BLs[blds[p]]);
    }
    if (AF32) {
#pragma unroll
      for (int u = 0; u < 2; u++) {
        const float4* ap = (const float4*)(afp[u] + k0);
        float4 a0 = ap[0], a1 = ap[1];
        uint hb0, lb0, hb1, lb1, hb2, lb2, hb3, lb3;
        split2(a0.x, a0.y, hb0, lb0); split2(a0.z, a0.w, hb1, lb1);
        split2(a1.x, a1.y, hb2, lb2); split2(a1.z, a1.w, hb3, lb3);
        *(uint4*)&AHs[adslot[u] << 3] = make_uint4(hb0, hb1, hb2, hb3);
        *(uint4*)&ALs[adslot[u] << 3] = make_uint4(lb0, lb1, lb2, lb3);
      }
    } else {
#pragma unroll
      for (int u = 0; u < 2; u++) {
        gload16(ash[u]  + k0, &AHs[alds[u]]);
        gload16(asl_[u] + k0, &ALs[alds[u]]);
      }
    }
    __syncthreads();

    short8 ah[4], al[4];
#pragma unroll
    for (int i = 0; i < 4; i++) {
      ah[i] = *(const short8*)&AHs[aslot[i] << 3];
      al[i] = *(const short8*)&ALs[aslot[i] << 3];
    }
#pragma unroll
    for (int j = 0; j < 4; j++) {
      short8 bh = *(const short8*)&BHs[bslot[j] << 3];
      short8 bl = *(const short8*)&BLs[bslot[j] << 3];
#pragma unroll
      for (int i = 0; i < 4; i++) {
        acc[i][j] = __builtin_amdgcn_mfma_f32_16x16x32_bf16(ah[i], bh, acc[i][j], 0, 0, 0);
        acc[i][j] = __builtin_amdgcn_mfma_f32_16x16x32_bf16(ah[i], bl, acc[i][j], 0, 0, 0);
        acc[i][j] = __builtin_amdgcn_mfma_f32_16x16x32_bf16(al[i], bh, acc[i][j], 0, 0, 0);
      }
    }
  }

  // epilogue: C/D layout col=lane&15, row=(lane>>4)*4+reg
  const int cq = lane >> 4;
#pragma unroll
  for (int j = 0; j < 4; j++) {
    const int col = n0 + wcol + (j << 4) + (lane & 15);
    const float bv = bias[col];
#pragma unroll
    for (int i = 0; i < 4; i++) {
#pragma unroll
      for (int r = 0; r < 4; r++) {
        const int row_g = m0 + wrow + (i << 4) + (cq << 2) + r;
        const size_t idx = (size_t)row_g * Nout + col;
        const float v = acc[i][j][r] + bv;
        if (OUTSPLIT) {
          uint bb = f2u(v);
          Ch[idx] = (ushort)(bb >> 16);
          Cl[idx] = (ushort)(f2u(v - u2f(bb & 0xffff0000u)) >> 16);
        } else {
          Cf[idx] = v;
        }
      }
    }
  }
}

// ---------------------------------------------------------------------------
// Flash-style block-causal attention (f32 math), qkv in split-bf16 planes.
// ---------------------------------------------------------------------------
__global__ __launch_bounds__(256)
void attn_f32(const ushort* __restrict__ QH, const ushort* __restrict__ QL,
              ushort* __restrict__ OH, ushort* __restrict__ OL) {
  __shared__ float qs[64][68];
  __shared__ float ksps[64][68];
  __shared__ float vst[64][68];
  __shared__ int   bi_s[N_];
  __shared__ int   tmin[9], tmax[9];
  __shared__ int   qmax_s, qmin_s;

  const int tid = threadIdx.x;
  const int tx  = tid & 15;
  const int ty  = tid >> 4;
  const int bh  = blockIdx.x;
  const int b   = bh / H_;
  const int h   = bh % H_;
  const int q0  = blockIdx.y << 6;

  for (int p = tid; p < N_; p += 256)
    bi_s[p] = (p / 96) * 6 + ((p % 24) >> 2);
  __syncthreads();
  if (tid < 9) {
    int mn = 1 << 30, mx = -1;
    for (int i = 0; i < 64; i++) { int v = bi_s[(tid<<6)+i]; mn = min(mn,v); mx = max(mx,v); }
    tmin[tid] = mn; tmax[tid] = mx;
  }
  if (tid == 9) {
    int mn = 1 << 30, mx = -1;
    for (int i = 0; i < 64; i++) { int v = bi_s[q0+i]; mn = min(mn,v); mx = max(mx,v); }
    qmin_s = mn; qmax_s = mx;
  }
  { // q tile
    const int row = tid >> 2;
    const int dc  = (tid & 3) << 4;
    const size_t base = (size_t)(b*N_ + q0 + row) * C3_ + h*HD_ + dc;
    const uint4* qh = (const uint4*)(QH + base);
    const uint4* ql = (const uint4*)(QL + base);
    float f[8];
#pragma unroll
    for (int u = 0; u < 2; u++) {
      unpack8(qh[u], ql[u], f);
      *(float4*)&qs[row][dc + (u<<3)]     = make_float4(f[0], f[1], f[2], f[3]);
      *(float4*)&qs[row][dc + (u<<3) + 4] = make_float4(f[4], f[5], f[6], f[7]);
    }
  }
  __syncthreads();

  int bi_q[4];
#pragma unroll
  for (int i = 0; i < 4; i++) bi_q[i] = bi_s[q0 + ty + (i<<4)];

  float o[4][4], mrun[4], lrun[4];
#pragma unroll
  for (int i = 0; i < 4; i++) {
    mrun[i] = -1e30f; lrun[i] = 0.f;
#pragma unroll
    for (int j = 0; j < 4; j++) o[i][j] = 0.f;
  }

  for (int kt = 0; kt < 9; ++kt) {
    if (tmin[kt] > qmax_s) continue;
    const bool nomask = (tmax[kt] <= qmin_s);
    __syncthreads();
    { // k,v tile
      const int row = tid >> 2;
      const int dc  = (tid & 3) << 4;
      const size_t kb = (size_t)(b*N_ + (kt<<6) + row) * C3_ + C_ + h*HD_ + dc;
      float f[8];
#pragma unroll
      for (int u = 0; u < 2; u++) {
        unpack8(((const uint4*)(QH + kb))[u], ((const uint4*)(QL + kb))[u], f);
        *(float4*)&ksps[row][dc + (u<<3)]     = make_float4(f[0], f[1], f[2], f[3]);
        *(float4*)&ksps[row][dc + (u<<3) + 4] = make_float4(f[4], f[5], f[6], f[7]);
      }
#pragma unroll
      for (int u = 0; u < 2; u++) {
        unpack8(((const uint4*)(QH + kb + C_))[u], ((const uint4*)(QL + kb + C_))[u], f);
#pragma unroll
        for (int e = 0; e < 8; e++) vst[dc + (u<<3) + e][row] = f[e];
      }
    }
    __syncthreads();

    float s[4][4];
#pragma unroll
    for (int i = 0; i < 4; i++)
#pragma unroll
      for (int j = 0; j < 4; j++) s[i][j] = 0.f;
#pragma unroll
    for (int d4 = 0; d4 < 16; ++d4) {
      float4 aa[4], bb[4];
#pragma unroll
      for (int i = 0; i < 4; i++) aa[i] = *(const float4*)&qs[ty + (i<<4)][d4<<2];
#pragma unroll
      for (int j = 0; j < 4; j++) bb[j] = *(const float4*)&ksps[tx + (j<<4)][d4<<2];
#pragma unroll
      for (int i = 0; i < 4; i++)
#pragma unroll
        for (int j = 0; j < 4; j++)
          s[i][j] = fmaf(aa[i].x, bb[j].x, fmaf(aa[i].y, bb[j].y,
                    fmaf(aa[i].z, bb[j].z, fmaf(aa[i].w, bb[j].w, s[i][j]))));
    }

    int bi_k[4];
#pragma unroll
    for (int j = 0; j < 4; j++) bi_k[j] = bi_s[(kt<<6) + tx + (j<<4)];
#pragma unroll
    for (int i = 0; i < 4; i++)
#pragma unroll
      for (int j = 0; j < 4; j++) {
        float v = s[i][j] * 0.125f;
        if (!nomask && (bi_k[j] > bi_q[i])) v = -1e30f;
        s[i][j] = v;
      }

#pragma unroll
    for (int i = 0; i < 4; i++) {
      float rm = fmaxf(fmaxf(s[i][0], s[i][1]), fmaxf(s[i][2], s[i][3]));
      rm = fmaxf(rm, __shfl_xor(rm, 1));
      rm = fmaxf(rm, __shfl_xor(rm, 2));
      rm = fmaxf(rm, __shfl_xor(rm, 4));
      rm = fmaxf(rm, __shfl_xor(rm, 8));
      const float mnew  = fmaxf(mrun[i], rm);
      const float alpha = __expf(mrun[i] - mnew);
      float rs = 0.f;
#pragma unroll
      for (int j = 0; j < 4; j++) { const float p = __expf(s[i][j] - mnew); s[i][j] = p; rs += p; }
      rs += __shfl_xor(rs, 1);
      rs += __shfl_xor(rs, 2);
      rs += __shfl_xor(rs, 4);
      rs += __shfl_xor(rs, 8);
      lrun[i] = lrun[i] * alpha + rs;
      mrun[i] = mnew;
#pragma unroll
      for (int j = 0; j < 4; j++) o[i][j] *= alpha;
    }

    __syncthreads();
#pragma unroll
    for (int i = 0; i < 4; i++)
#pragma unroll
      for (int j = 0; j < 4; j++) ksps[ty + (i<<4)][tx + (j<<4)] = s[i][j];
    __syncthreads();

#pragma unroll
    for (int k4 = 0; k4 < 16; ++k4) {
      float4 pa[4], vb[4];
#pragma unroll
      for (int i = 0; i < 4; i++) pa[i] = *(const float4*)&ksps[ty + (i<<4)][k4<<2];
#pragma unroll
      for (int j = 0; j < 4; j++) vb[j] = *(const float4*)&vst[tx + (j<<4)][k4<<2];
#pragma unroll
      for (int i = 0; i < 4; i++)
#pragma unroll
        for (int j = 0; j < 4; j++)
          o[i][j] = fmaf(pa[i].x, vb[j].x, fmaf(pa[i].y, vb[j].y,
                    fmaf(pa[i].z, vb[j].z, fmaf(pa[i].w, vb[j].w, o[i][j]))));
    }
  }

  // normalize + write split planes
#pragma unroll
  for (int i = 0; i < 4; i++) {
    const float inv = 1.f / lrun[i];
    const size_t ob = (size_t)(b*N_ + q0 + ty + (i<<4)) * C_ + h*HD_ + tx;
#pragma unroll
    for (int j = 0; j < 4; j++) {
      const float v = o[i][j] * inv;
      const uint bb = f2u(v);
      OH[ob + (j<<4)] = (ushort)(bb >> 16);
      OL[ob + (j<<4)] = (ushort)(f2u(v - u2f(bb & 0xffff0000u)) >> 16);
    }
  }
}

// ---------------------------------------------------------------------------
extern "C" void kernel_launch(void* const* d_in, const int* in_sizes, int n_in,
                              void* d_out, int out_size, void* d_ws, size_t ws_size,
                              hipStream_t stream) {
  const float* x      = (const float*)d_in[0];
  const float* qkv_w  = (const float*)d_in[1];
  const float* qkv_b  = (const float*)d_in[2];
  const float* proj_w = (const float*)d_in[3];
  const float* proj_b = (const float*)d_in[4];
  float* out = (float*)d_out;

  // ws layout (peak 226.5 MB == round-1 proven footprint):
  // [QH 85MB][QL 85MB][{QWH+QWL 7.1MB during QKV} -> {AHp+ALp 56.6MB after}]
  // [PWH+PWL 2.4MB at offset 0, written after attention (qkv planes dead)]
  ushort* ws = (ushort*)d_ws;
  const size_t nQKV = (size_t)M_ * C3_;
  const size_t nAO  = (size_t)M_ * C_;
  ushort* QH  = ws;
  ushort* QL  = QH + nQKV;
  ushort* QWH = QL + nQKV;
  ushort* QWL = QWH + (size_t)C3_ * C_;
  ushort* AHp = QL + nQKV;          // overlays QWH/QWL (dead after QKV GEMM)
  ushort* ALp = AHp + nAO;
  ushort* PWH = ws;                 // overlays QH (dead after attention)
  ushort* PWL = PWH + (size_t)C_ * C_;

  // 1) split qkv_w
  split_f32<<<(C3_*C_/4 + 255)/256, 256, 0, stream>>>(qkv_w, QWH, QWL, C3_*C_/4);
  // 2) qkv = x @ qkv_w^T + b   (A=f32 x, in-kernel split; out = split planes)
  gemm_mfma<true, true><<<dim3(C3_/128, M_/128), 256, 0, stream>>>(
      x, nullptr, nullptr, QWH, QWL, qkv_b, nullptr, QH, QL, C3_);
  // 3) attention (reads qkv planes, writes attn planes)
  attn_f32<<<dim3(B_*H_, N_/64), 256, 0, stream>>>(QH, QL, AHp, ALp);
  // 4) split proj_w into the now-dead qkv region
  split_f32<<<(C_*C_/4 + 255)/256, 256, 0, stream>>>(proj_w, PWH, PWL, C_*C_/4);
  // 5) out = attn @ proj_w^T + b  (A pre-split; f32 out)
  gemm_mfma<false, false><<<dim3(C_/128, M_/128), 256, 0, stream>>>(
      nullptr, AHp, ALp, PWH, PWL, proj_b, out, nullptr, nullptr, C_);
}

// Round 3
// 596.668 us; speedup vs baseline: 2.5720x; 1.4200x over previous
//
#include <hip/hip_runtime.h>
#include <stdint.h>

#define B_  32
#define N_  576
#define C_  768
#define H_  12
#define HD_ 64
#define M_  (B_*N_)    // 18432
#define C3_ (3*C_)     // 2304
#define K_  768

typedef __attribute__((ext_vector_type(8))) short short8;
typedef __attribute__((ext_vector_type(4))) float f32x4;

__device__ __forceinline__ uint  f2u(float x){ return __float_as_uint(x); }
__device__ __forceinline__ float u2f(uint x){ return __uint_as_float(x); }

// truncation split: hi = top16(a), lo = bf16(a - hi); combined rel err <= 2^-16
__device__ __forceinline__ void split1(float a, ushort& h, ushort& l) {
  uint b0 = f2u(a);
  h = (ushort)(b0 >> 16);
  l = (ushort)(f2u(a - u2f(b0 & 0xffff0000u)) >> 16);
}
__device__ __forceinline__ void split2(float a, float b, uint& hw, uint& lw) {
  uint b0 = f2u(a), b1 = f2u(b);
  uint t0 = b0 & 0xffff0000u, t1 = b1 & 0xffff0000u;
  hw = (b0 >> 16) | t1;
  lw = (f2u(a - u2f(t0)) >> 16) | (f2u(b - u2f(t1)) & 0xffff0000u);
}
// bf16 round-to-nearest-even (for P in [0,1])
__device__ __forceinline__ ushort bf16rn(float x) {
  uint u = f2u(x);
  return (ushort)((u + 0x7fffu + ((u >> 16) & 1u)) >> 16);
}

// async global->LDS 16B DMA; LDS dest is wave-uniform base + lane*16
__device__ __forceinline__ void gload16(const ushort* g, ushort* l) {
  auto gp = (const __attribute__((address_space(1))) uint*)(g);
  auto lp = reinterpret_cast<__attribute__((address_space(3))) uint*>(
              reinterpret_cast<uintptr_t>(l));
  __builtin_amdgcn_global_load_lds(gp, lp, 16, 0, 0);
}

// swizzled 64x64 bf16 tile: logical (row, chunk c of 8 ushorts) lives at
// slot row*8 + (c ^ (row&7)).  DMA writes linear slots with the matching
// global chunk, so both staging and ds_read_b128 frag reads are <=2-way.
__device__ __forceinline__ short8 frag_read(const ushort* t, int row, int c) {
  return *(const short8*)&t[((row << 3) + (c ^ (row & 7))) << 3];
}

// elementwise f32 -> (hi,lo) bf16 planes (for weights)
__global__ __launch_bounds__(256)
void split_f32(const float* __restrict__ src, ushort* __restrict__ hi,
               ushort* __restrict__ lo, int n4) {
  int i = blockIdx.x * 256 + threadIdx.x;
  if (i >= n4) return;
  float4 a = ((const float4*)src)[i];
  uint h0, l0, h1, l1;
  split2(a.x, a.y, h0, l0); split2(a.z, a.w, h1, l1);
  ((uint2*)hi)[i] = make_uint2(h0, h1);
  ((uint2*)lo)[i] = make_uint2(l0, l1);
}

// ---------------------------------------------------------------------------
// Split-bf16 MFMA GEMM core. MODE 0: A=f32 (in-kernel split), epilogue scatters
// q/k -> (b,h,n,d) planes (q pre-scaled 0.125), v -> transposed (b,h,d,n).
// MODE 1: A = pre-split planes, f32 output (proj).
// ---------------------------------------------------------------------------
template<int MODE>
__global__ __launch_bounds__(256)
void gemm_mfma(const float* __restrict__ Af, const ushort* __restrict__ Ah,
               const ushort* __restrict__ Al, const ushort* __restrict__ Bh,
               const ushort* __restrict__ Bl, const float* __restrict__ bias,
               float* __restrict__ Cf,
               ushort* __restrict__ QpH, ushort* __restrict__ QpL,
               ushort* __restrict__ KpH, ushort* __restrict__ KpL,
               ushort* __restrict__ VtH, ushort* __restrict__ VtL,
               int Nout) {
  __shared__ ushort AHs[128*32], ALs[128*32], BHs[128*32], BLs[128*32];

  const int tid  = threadIdx.x;
  const int lane = tid & 63, wave = tid >> 6;
  const int ln15 = lane & 15, cq = lane >> 4;
  const int wrow = (wave >> 1) << 6, wcol = (wave & 1) << 6;
  const int m0 = blockIdx.y << 7, n0 = blockIdx.x << 7;

  int aslot[4], bslot[4];
#pragma unroll
  for (int i = 0; i < 4; i++) {
    int r = wrow + (i << 4) + ln15;
    aslot[i] = (r << 2) + ((lane >> 4) ^ ((r >> 1) & 3));
  }
#pragma unroll
  for (int j = 0; j < 4; j++) {
    int r = wcol + (j << 4) + ln15;
    bslot[j] = (r << 2) + ((lane >> 4) ^ ((r >> 1) & 3));
  }

  int blds[2]; const ushort *bsh[2], *bsl[2];
#pragma unroll
  for (int p = 0; p < 2; p++) {
    int bs = ((wave << 1) + p) << 6;
    int s = bs + lane, row = s >> 2, c = (s & 3) ^ ((row >> 1) & 3);
    blds[p] = bs << 3;
    bsh[p] = Bh + (size_t)(n0 + row) * K_ + (c << 3);
    bsl[p] = Bl + (size_t)(n0 + row) * K_ + (c << 3);
  }

  const float* afp[2]; int adslot[2];
  int alds[2]; const ushort *ash[2], *asl_[2];
#pragma unroll
  for (int u = 0; u < 2; u++) {
    if (MODE == 0) {
      int t2 = tid + (u << 8), ar = t2 >> 2, ac = t2 & 3;
      afp[u] = Af + (size_t)(m0 + ar) * K_ + (ac << 3);
      adslot[u] = (ar << 2) + (ac ^ ((ar >> 1) & 3));
    } else {
      int bs = ((wave << 1) + u) << 6;
      int s = bs + lane, row = s >> 2, c = (s & 3) ^ ((row >> 1) & 3);
      alds[u] = bs << 3;
      ash[u]  = Ah + (size_t)(m0 + row) * K_ + (c << 3);
      asl_[u] = Al + (size_t)(m0 + row) * K_ + (c << 3);
    }
  }

  f32x4 acc[4][4];
#pragma unroll
  for (int i = 0; i < 4; i++)
#pragma unroll
    for (int j = 0; j < 4; j++) acc[i][j] = (f32x4)0.f;

  for (int k0 = 0; k0 < K_; k0 += 32) {
    __syncthreads();
#pragma unroll
    for (int p = 0; p < 2; p++) {
      gload16(bsh[p] + k0, &BHs[blds[p]]);
      gload16(bsl[p] + k0, &BLs[blds[p]]);
    }
    if (MODE == 0) {
#pragma unroll
      for (int u = 0; u < 2; u++) {
        const float4* ap = (const float4*)(afp[u] + k0);
        float4 a0 = ap[0], a1 = ap[1];
        uint hb0, lb0, hb1, lb1, hb2, lb2, hb3, lb3;
        split2(a0.x, a0.y, hb0, lb0); split2(a0.z, a0.w, hb1, lb1);
        split2(a1.x, a1.y, hb2, lb2); split2(a1.z, a1.w, hb3, lb3);
        *(uint4*)&AHs[adslot[u] << 3] = make_uint4(hb0, hb1, hb2, hb3);
        *(uint4*)&ALs[adslot[u] << 3] = make_uint4(lb0, lb1, lb2, lb3);
      }
    } else {
#pragma unroll
      for (int u = 0; u < 2; u++) {
        gload16(ash[u]  + k0, &AHs[alds[u]]);
        gload16(asl_[u] + k0, &ALs[alds[u]]);
      }
    }
    __syncthreads();

    short8 ah[4], al[4];
#pragma unroll
    for (int i = 0; i < 4; i++) {
      ah[i] = *(const short8*)&AHs[aslot[i] << 3];
      al[i] = *(const short8*)&ALs[aslot[i] << 3];
    }
#pragma unroll
    for (int j = 0; j < 4; j++) {
      short8 bh = *(const short8*)&BHs[bslot[j] << 3];
      short8 bl = *(const short8*)&BLs[bslot[j] << 3];
#pragma unroll
      for (int i = 0; i < 4; i++) {
        acc[i][j] = __builtin_amdgcn_mfma_f32_16x16x32_bf16(ah[i], bh, acc[i][j], 0, 0, 0);
        acc[i][j] = __builtin_amdgcn_mfma_f32_16x16x32_bf16(ah[i], bl, acc[i][j], 0, 0, 0);
        acc[i][j] = __builtin_amdgcn_mfma_f32_16x16x32_bf16(al[i], bh, acc[i][j], 0, 0, 0);
      }
    }
  }

  // epilogue: C/D layout col=lane&15, row=(lane>>4)*4+reg
  if (MODE == 1) {
#pragma unroll
    for (int j = 0; j < 4; j++) {
      const int col = n0 + wcol + (j << 4) + ln15;
      const float bv = bias[col];
#pragma unroll
      for (int i = 0; i < 4; i++)
#pragma unroll
        for (int r = 0; r < 4; r++) {
          const int row_g = m0 + wrow + (i << 4) + (cq << 2) + r;
          Cf[(size_t)row_g * Nout + col] = acc[i][j][r] + bv;
        }
    }
  } else {
#pragma unroll
    for (int j = 0; j < 4; j++) {
      const int col = n0 + wcol + (j << 4) + ln15;
      const int which = col / 768;              // block-uniform
      const int hh = (col % 768) >> 6;
      const int dd = col & 63;
      const float bv = bias[col];
      const float scale = (which == 0) ? 0.125f : 1.f;
#pragma unroll
      for (int i = 0; i < 4; i++) {
        const int base_row = m0 + wrow + (i << 4) + (cq << 2);
        const int b = base_row / 576;           // constant across r (4 | 576)
        const int n = base_row - b * 576;
        const size_t bh = (size_t)b * H_ + hh;
        if (which == 2) {                       // V -> transposed (b,h,d,n)
          ushort hv[4], lv[4];
#pragma unroll
          for (int r = 0; r < 4; r++) split1(acc[i][j][r] + bv, hv[r], lv[r]);
          const size_t dst = (bh * 64 + dd) * 576 + n;
          *(ushort4*)&VtH[dst] = make_ushort4(hv[0], hv[1], hv[2], hv[3]);
          *(ushort4*)&VtL[dst] = make_ushort4(lv[0], lv[1], lv[2], lv[3]);
        } else {                                // Q/K -> (b,h,n,d)
          ushort* dh = which ? KpH : QpH;
          ushort* dl = which ? KpL : QpL;
#pragma unroll
          for (int r = 0; r < 4; r++) {
            ushort hs, ls;
            split1((acc[i][j][r] + bv) * scale, hs, ls);
            const size_t dst = (bh * 576 + n + r) * 64 + dd;
            dh[dst] = hs; dl[dst] = ls;
          }
        }
      }
    }
  }
}

// ---------------------------------------------------------------------------
// MFMA flash attention, block-causal. One block = (qtile, b*h). 4 waves,
// each wave owns 16 query rows. Q/K split-bf16 (3-product S), P plain bf16,
// V split (2-product PV). P stays within its own wave -> no barrier.
// ---------------------------------------------------------------------------
__global__ __launch_bounds__(256)
void attn_mfma(const ushort* __restrict__ QH, const ushort* __restrict__ QL,
               const ushort* __restrict__ KHp, const ushort* __restrict__ KLp,
               const ushort* __restrict__ VHp, const ushort* __restrict__ VLp,
               ushort* __restrict__ OH, ushort* __restrict__ OL) {
  __shared__ ushort qh_s[64*64], ql_s[64*64];
  __shared__ ushort kh_s[64*64], kl_s[64*64];
  __shared__ ushort vh_s[64*64], vl_s[64*64];
  __shared__ ushort p_s[64*64];

  const int tid  = threadIdx.x;
  const int lane = tid & 63, wave = tid >> 6;
  const int ln15 = lane & 15, quad = lane >> 4;
  const int qt = blockIdx.x;                  // 0..8
  const int bh = blockIdx.y;                  // 0..383
  const int q0 = qt << 6;
  const size_t pbase = (size_t)bh * (576 * 64);   // same for q/k/vt planes

  // stage Q (hi/lo)
  {
    const int base_s = ((wave << 1) + 0) << 6;   // handled below per p
#pragma unroll
    for (int p = 0; p < 2; p++) {
      const int bs = ((wave << 1) + p) << 6;
      const int s = bs + lane, row = s >> 3, c = (s & 7) ^ (row & 7);
      const size_t off = pbase + (size_t)(q0 + row) * 64 + (c << 3);
      gload16(QH + off, &qh_s[bs << 3]);
      gload16(QL + off, &ql_s[bs << 3]);
    }
    (void)base_s;
  }

  int bi_q[4];
#pragma unroll
  for (int r = 0; r < 4; r++) {
    const int p = q0 + (wave << 4) + (quad << 2) + r;
    bi_q[r] = (p / 96) * 6 + ((p % 24) >> 2);
  }
  const int qmax = 6 * ((qt * 64 + 159) / 96) - 1;
  const int qmin = 6 * ((2 * qt) / 3);

  f32x4 oacc[4];
#pragma unroll
  for (int dt = 0; dt < 4; dt++) oacc[dt] = (f32x4)0.f;
  float mrun[4], lrun[4];
#pragma unroll
  for (int r = 0; r < 4; r++) { mrun[r] = -1e30f; lrun[r] = 0.f; }

#pragma unroll
  for (int kt = 0; kt < 9; ++kt) {
    const int tmink = 6 * ((2 * kt) / 3);
    const int tmaxk = 6 * ((kt * 64 + 159) / 96) - 1;
    if (tmink > qmax) continue;               // future block-tile: skip
    const bool nomask = (tmaxk <= qmin);

    __syncthreads();                          // prev K/V reads done
#pragma unroll
    for (int p = 0; p < 2; p++) {
      const int bs = ((wave << 1) + p) << 6;
      const int s = bs + lane, row = s >> 3, c = (s & 7) ^ (row & 7);
      const size_t koff = pbase + (size_t)((kt << 6) + row) * 64 + (c << 3);
      gload16(KHp + koff, &kh_s[bs << 3]);
      gload16(KLp + koff, &kl_s[bs << 3]);
      const size_t voff = pbase + (size_t)row * 576 + (kt << 6) + (c << 3);
      gload16(VHp + voff, &vh_s[bs << 3]);
      gload16(VLp + voff, &vl_s[bs << 3]);
    }
    __syncthreads();                          // DMA drained

    // S = Q K^T  (pre-scaled by 0.125 via Q)
    f32x4 sacc[4];
#pragma unroll
    for (int j = 0; j < 4; j++) sacc[j] = (f32x4)0.f;
#pragma unroll
    for (int s2 = 0; s2 < 2; ++s2) {
      const short8 aqh = frag_read(qh_s, (wave << 4) + ln15, (s2 << 2) + quad);
      const short8 aql = frag_read(ql_s, (wave << 4) + ln15, (s2 << 2) + quad);
#pragma unroll
      for (int j = 0; j < 4; j++) {
        const short8 bkh = frag_read(kh_s, (j << 4) + ln15, (s2 << 2) + quad);
        const short8 bkl = frag_read(kl_s, (j << 4) + ln15, (s2 << 2) + quad);
        sacc[j] = __builtin_amdgcn_mfma_f32_16x16x32_bf16(aqh, bkh, sacc[j], 0, 0, 0);
        sacc[j] = __builtin_amdgcn_mfma_f32_16x16x32_bf16(aqh, bkl, sacc[j], 0, 0, 0);
        sacc[j] = __builtin_amdgcn_mfma_f32_16x16x32_bf16(aql, bkh, sacc[j], 0, 0, 0);
      }
    }

    float sv[4][4];
#pragma unroll
    for (int j = 0; j < 4; j++)
#pragma unroll
      for (int r = 0; r < 4; r++) sv[j][r] = sacc[j][r];

    if (!nomask) {
      int bi_k[4];
#pragma unroll
      for (int j = 0; j < 4; j++) {
        const int p = (kt << 6) + (j << 4) + ln15;
        bi_k[j] = (p / 96) * 6 + ((p % 24) >> 2);
      }
#pragma unroll
      for (int j = 0; j < 4; j++)
#pragma unroll
        for (int r = 0; r < 4; r++)
          if (bi_k[j] > bi_q[r]) sv[j][r] = -1e30f;
    }

    // online softmax; row r lives in the 16 lanes of this quad
#pragma unroll
    for (int r = 0; r < 4; r++) {
      float rm = fmaxf(fmaxf(sv[0][r], sv[1][r]), fmaxf(sv[2][r], sv[3][r]));
      rm = fmaxf(rm, __shfl_xor(rm, 1));
      rm = fmaxf(rm, __shfl_xor(rm, 2));
      rm = fmaxf(rm, __shfl_xor(rm, 4));
      rm = fmaxf(rm, __shfl_xor(rm, 8));
      const float mnew  = fmaxf(mrun[r], rm);
      const float alpha = __expf(mrun[r] - mnew);
      float rs = 0.f;
#pragma unroll
      for (int j = 0; j < 4; j++) {
        const float pj = __expf(sv[j][r] - mnew);
        sv[j][r] = pj; rs += pj;
      }
      rs += __shfl_xor(rs, 1);
      rs += __shfl_xor(rs, 2);
      rs += __shfl_xor(rs, 4);
      rs += __shfl_xor(rs, 8);
      lrun[r] = lrun[r] * alpha + rs;
      mrun[r] = mnew;
#pragma unroll
      for (int dt = 0; dt < 4; dt++) oacc[dt][r] *= alpha;
    }

    // P (bf16) -> own rows of p_s; wave-private, so only a waitcnt is needed
#pragma unroll
    for (int j = 0; j < 4; j++)
#pragma unroll
      for (int r = 0; r < 4; r++) {
        const int row = (wave << 4) + (quad << 2) + r;
        const int col = (j << 4) + ln15;
        const int c = col >> 3, e = col & 7;
        p_s[(((row << 3) + (c ^ (row & 7))) << 3) + e] = bf16rn(sv[j][r]);
      }
    asm volatile("s_waitcnt lgkmcnt(0)" ::: "memory");

    // O += P V
#pragma unroll
    for (int s2 = 0; s2 < 2; ++s2) {
      const short8 pf = frag_read(p_s, (wave << 4) + ln15, (s2 << 2) + quad);
#pragma unroll
      for (int dt = 0; dt < 4; dt++) {
        const short8 bvh = frag_read(vh_s, (dt << 4) + ln15, (s2 << 2) + quad);
        const short8 bvl = frag_read(vl_s, (dt << 4) + ln15, (s2 << 2) + quad);
        oacc[dt] = __builtin_amdgcn_mfma_f32_16x16x32_bf16(pf, bvh, oacc[dt], 0, 0, 0);
        oacc[dt] = __builtin_amdgcn_mfma_f32_16x16x32_bf16(pf, bvl, oacc[dt], 0, 0, 0);
      }
    }
  }

  // normalize + write split planes, token-major (M, C) for the proj GEMM
  const int b = bh / H_, h = bh % H_;
#pragma unroll
  for (int r = 0; r < 4; r++) {
    const float inv = 1.f / lrun[r];
    const int row_g = b * 576 + q0 + (wave << 4) + (quad << 2) + r;
#pragma unroll
    for (int dt = 0; dt < 4; dt++) {
      const float v = oacc[dt][r] * inv;
      ushort hs, ls;
      split1(v, hs, ls);
      const size_t dst = (size_t)row_g * 768 + h * 64 + (dt << 4) + ln15;
      OH[dst] = hs; OL[dst] = ls;
    }
  }
}

// ---------------------------------------------------------------------------
extern "C" void kernel_launch(void* const* d_in, const int* in_sizes, int n_in,
                              void* d_out, int out_size, void* d_ws, size_t ws_size,
                              hipStream_t stream) {
  const float* x      = (const float*)d_in[0];
  const float* qkv_w  = (const float*)d_in[1];
  const float* qkv_b  = (const float*)d_in[2];
  const float* proj_w = (const float*)d_in[3];
  const float* proj_b = (const float*)d_in[4];
  float* out = (float*)d_out;

  // ws: 6 qkv planes (b,h,n,d)/(b,h,d,n) + [QW split | attn-out planes]
  // peak = 8 * 28.3MB = 226.5MB (same as round 2)
  ushort* ws = (ushort*)d_ws;
  const size_t nP = (size_t)B_ * H_ * 576 * 64;   // 14,155,776
  ushort* QpH = ws + 0 * nP;
  ushort* QpL = ws + 1 * nP;
  ushort* KpH = ws + 2 * nP;
  ushort* KpL = ws + 3 * nP;
  ushort* VtH = ws + 4 * nP;
  ushort* VtL = ws + 5 * nP;
  ushort* QWH = ws + 6 * nP;                      // qkv_w split (dead after GEMM1)
  ushort* QWL = QWH + (size_t)C3_ * C_;
  ushort* AH  = ws + 6 * nP;                      // attn out planes (overlay QW)
  ushort* AL  = ws + 7 * nP;
  ushort* PWH = ws;                               // proj_w split (overlay Qp, post-attn)
  ushort* PWL = PWH + (size_t)C_ * C_;

  split_f32<<<(C3_*C_/4 + 255)/256, 256, 0, stream>>>(qkv_w, QWH, QWL, C3_*C_/4);

  gemm_mfma<0><<<dim3(C3_/128, M_/128), 256, 0, stream>>>(
      x, nullptr, nullptr, QWH, QWL, qkv_b, nullptr,
      QpH, QpL, KpH, KpL, VtH, VtL, C3_);

  attn_mfma<<<dim3(9, B_*H_), 256, 0, stream>>>(
      QpH, QpL, KpH, KpL, VtH, VtL, AH, AL);

  split_f32<<<(C_*C_/4 + 255)/256, 256, 0, stream>>>(proj_w, PWH, PWL, C_*C_/4);

  gemm_mfma<1><<<dim3(C_/128, M_/128), 256, 0, stream>>>(
      nullptr, AH, AL, PWH, PWL, proj_b, out,
      nullptr, nullptr, nullptr, nullptr, nullptr, nullptr, C_);
}

// Round 5
// 553.428 us; speedup vs baseline: 2.7729x; 1.0781x over previous
//
#include <hip/hip_runtime.h>
#include <stdint.h>

#define B_  32
#define N_  576
#define C_  768
#define H_  12
#define HD_ 64
#define M_  (B_*N_)    // 18432
#define C3_ (3*C_)     // 2304
#define K_  768

typedef __attribute__((ext_vector_type(8))) short short8;
typedef __attribute__((ext_vector_type(4))) float f32x4;

__device__ __forceinline__ uint  f2u(float x){ return __float_as_uint(x); }
__device__ __forceinline__ float u2f(uint x){ return __uint_as_float(x); }

// explicit DMA/LDS drain (defense-in-depth; merges with compiler waits)
__device__ __forceinline__ void drain_all() {
  asm volatile("s_waitcnt vmcnt(0) lgkmcnt(0)" ::: "memory");
}

// truncation split: hi = top16(a), lo = bf16(a - hi); combined rel err <= 2^-16
__device__ __forceinline__ void split1(float a, ushort& h, ushort& l) {
  uint b0 = f2u(a);
  h = (ushort)(b0 >> 16);
  l = (ushort)(f2u(a - u2f(b0 & 0xffff0000u)) >> 16);
}
__device__ __forceinline__ void split2(float a, float b, uint& hw, uint& lw) {
  uint b0 = f2u(a), b1 = f2u(b);
  uint t0 = b0 & 0xffff0000u, t1 = b1 & 0xffff0000u;
  hw = (b0 >> 16) | t1;
  lw = (f2u(a - u2f(t0)) >> 16) | (f2u(b - u2f(t1)) & 0xffff0000u);
}
// bf16 round-to-nearest-even
__device__ __forceinline__ ushort bf16rn(float x) {
  uint u = f2u(x);
  return (ushort)((u + 0x7fffu + ((u >> 16) & 1u)) >> 16);
}

// async global->LDS 16B DMA; LDS dest is wave-uniform base + lane*16
__device__ __forceinline__ void gload16(const ushort* g, ushort* l) {
  auto gp = (const __attribute__((address_space(1))) uint*)(g);
  auto lp = reinterpret_cast<__attribute__((address_space(3))) uint*>(
              reinterpret_cast<uintptr_t>(l));
  __builtin_amdgcn_global_load_lds(gp, lp, 16, 0, 0);
}

// swizzled 64x64 bf16 tile: logical (row, chunk c of 8 ushorts) at slot
// row*8 + (c ^ (row&7)); DMA writes linear slots carrying the matching chunk.
__device__ __forceinline__ short8 frag_read(const ushort* t, int row, int c) {
  return *(const short8*)&t[((row << 3) + (c ^ (row & 7))) << 3];
}

// elementwise f32 -> (hi,lo) bf16 planes
__global__ __launch_bounds__(256)
void split_f32(const float* __restrict__ src, ushort* __restrict__ hi,
               ushort* __restrict__ lo, int n4) {
  int i = blockIdx.x * 256 + threadIdx.x;
  if (i >= n4) return;
  float4 a = ((const float4*)src)[i];
  uint h0, l0, h1, l1;
  split2(a.x, a.y, h0, l0); split2(a.z, a.w, h1, l1);
  ((uint2*)hi)[i] = make_uint2(h0, h1);
  ((uint2*)lo)[i] = make_uint2(l0, l1);
}

// ---------------------------------------------------------------------------
// Split-bf16 MFMA GEMM, pure-DMA staging (all operands pre-split planes).
// 128x128 tile, BK=32, 4 waves x 4x4 tiles of 16x16x32 bf16, 3 products.
// EPI 0: scatter q/k (split, q pre-scaled 0.125) + v (single bf16, transposed)
// EPI 1: f32 output + bias (proj)
// ---------------------------------------------------------------------------
template<int EPI>
__global__ __launch_bounds__(256)
void gemm_mfma(const ushort* __restrict__ Ah, const ushort* __restrict__ Al,
               const ushort* __restrict__ Bh, const ushort* __restrict__ Bl,
               const float* __restrict__ bias, float* __restrict__ Cf,
               ushort* __restrict__ QpH, ushort* __restrict__ QpL,
               ushort* __restrict__ KpH, ushort* __restrict__ KpL,
               ushort* __restrict__ Vt, int Nout) {
  __shared__ ushort AHs[128*32], ALs[128*32], BHs[128*32], BLs[128*32];

  const int tid  = threadIdx.x;
  const int lane = tid & 63, wave = tid >> 6;
  const int ln15 = lane & 15, cq = lane >> 4;
  const int wrow = (wave >> 1) << 6, wcol = (wave & 1) << 6;
  const int m0 = blockIdx.y << 7, n0 = blockIdx.x << 7;

  int aslot[4], bslot[4];
#pragma unroll
  for (int i = 0; i < 4; i++) {
    int r = wrow + (i << 4) + ln15;
    aslot[i] = (r << 2) + ((lane >> 4) ^ ((r >> 1) & 3));
  }
#pragma unroll
  for (int j = 0; j < 4; j++) {
    int r = wcol + (j << 4) + ln15;
    bslot[j] = (r << 2) + ((lane >> 4) ^ ((r >> 1) & 3));
  }

  // staging: per wave 2 parts x (A hi/lo + B hi/lo) 1KB DMAs
  int lds[2]; const ushort *pAh[2], *pAl[2], *pBh[2], *pBl[2];
#pragma unroll
  for (int p = 0; p < 2; p++) {
    int bs = ((wave << 1) + p) << 6;
    int s = bs + lane, row = s >> 2, c = (s & 3) ^ ((row >> 1) & 3);
    lds[p] = bs << 3;
    pAh[p] = Ah + (size_t)(m0 + row) * K_ + (c << 3);
    pAl[p] = Al + (size_t)(m0 + row) * K_ + (c << 3);
    pBh[p] = Bh + (size_t)(n0 + row) * K_ + (c << 3);
    pBl[p] = Bl + (size_t)(n0 + row) * K_ + (c << 3);
  }

  f32x4 acc[4][4];
#pragma unroll
  for (int i = 0; i < 4; i++)
#pragma unroll
    for (int j = 0; j < 4; j++) acc[i][j] = (f32x4)0.f;

  for (int k0 = 0; k0 < K_; k0 += 32) {
    drain_all();
    __syncthreads();                        // prev frag reads done
#pragma unroll
    for (int p = 0; p < 2; p++) {
      gload16(pAh[p] + k0, &AHs[lds[p]]);
      gload16(pAl[p] + k0, &ALs[lds[p]]);
      gload16(pBh[p] + k0, &BHs[lds[p]]);
      gload16(pBl[p] + k0, &BLs[lds[p]]);
    }
    drain_all();                            // DMAs drained before barrier
    __syncthreads();

    short8 ah[4], al[4];
#pragma unroll
    for (int i = 0; i < 4; i++) {
      ah[i] = *(const short8*)&AHs[aslot[i] << 3];
      al[i] = *(const short8*)&ALs[aslot[i] << 3];
    }
#pragma unroll
    for (int j = 0; j < 4; j++) {
      short8 bh = *(const short8*)&BHs[bslot[j] << 3];
      short8 bl = *(const short8*)&BLs[bslot[j] << 3];
#pragma unroll
      for (int i = 0; i < 4; i++) {
        acc[i][j] = __builtin_amdgcn_mfma_f32_16x16x32_bf16(ah[i], bh, acc[i][j], 0, 0, 0);
        acc[i][j] = __builtin_amdgcn_mfma_f32_16x16x32_bf16(ah[i], bl, acc[i][j], 0, 0, 0);
        acc[i][j] = __builtin_amdgcn_mfma_f32_16x16x32_bf16(al[i], bh, acc[i][j], 0, 0, 0);
      }
    }
  }

  // epilogue: C/D layout col=lane&15, row=(lane>>4)*4+reg
  if (EPI == 1) {
#pragma unroll
    for (int j = 0; j < 4; j++) {
      const int col = n0 + wcol + (j << 4) + ln15;
      const float bv = bias[col];
#pragma unroll
      for (int i = 0; i < 4; i++)
#pragma unroll
        for (int r = 0; r < 4; r++) {
          const int row_g = m0 + wrow + (i << 4) + (cq << 2) + r;
          Cf[(size_t)row_g * Nout + col] = acc[i][j][r] + bv;
        }
    }
  } else {
#pragma unroll
    for (int j = 0; j < 4; j++) {
      const int col = n0 + wcol + (j << 4) + ln15;
      const int which = col / 768;              // block-uniform
      const int hh = (col % 768) >> 6;
      const int dd = col & 63;
      const float bv = bias[col];
      const float scale = (which == 0) ? 0.125f : 1.f;
#pragma unroll
      for (int i = 0; i < 4; i++) {
        const int base_row = m0 + wrow + (i << 4) + (cq << 2);
        const int b = base_row / 576;           // constant across r (4 | 576)
        const int n = base_row - b * 576;
        const size_t bh = (size_t)b * H_ + hh;
        if (which == 2) {                       // V -> single bf16, (b,h,d,n)
          ushort hv[4];
#pragma unroll
          for (int r = 0; r < 4; r++) hv[r] = bf16rn(acc[i][j][r] + bv);
          const size_t dst = (bh * 64 + dd) * 576 + n;
          *(ushort4*)&Vt[dst] = make_ushort4(hv[0], hv[1], hv[2], hv[3]);
        } else {                                // Q/K -> split planes (b,h,n,d)
          ushort* dh = which ? KpH : QpH;
          ushort* dl = which ? KpL : QpL;
#pragma unroll
          for (int r = 0; r < 4; r++) {
            ushort hs, ls;
            split1((acc[i][j][r] + bv) * scale, hs, ls);
            const size_t dst = (bh * 576 + n + r) * 64 + dd;
            dh[dst] = hs; dl[dst] = ls;
          }
        }
      }
    }
  }
}

// ---------------------------------------------------------------------------
// MFMA flash attention, block-causal. Q/K split (3-product S), V+P plain bf16
// (1-product PV). P stays wave-private -> lgkm wait only. p_s padded +8KB to
// hold LDS at 56KB -> 2 blocks/CU (round-3 proven occupancy regime).
// ---------------------------------------------------------------------------
__global__ __launch_bounds__(256)
void attn_mfma(const ushort* __restrict__ QH, const ushort* __restrict__ QL,
               const ushort* __restrict__ KHp, const ushort* __restrict__ KLp,
               const ushort* __restrict__ Vp,
               ushort* __restrict__ OH, ushort* __restrict__ OL) {
  __shared__ ushort qh_s[64*64], ql_s[64*64];
  __shared__ ushort kh_s[64*64], kl_s[64*64];
  __shared__ ushort vh_s[64*64];
  __shared__ ushort p_s[64*64 + 4096];     // +8KB pad: keep 2 blocks/CU

  const int tid  = threadIdx.x;
  const int lane = tid & 63, wave = tid >> 6;
  const int ln15 = lane & 15, quad = lane >> 4;
  const int qt = blockIdx.x;                  // 0..8
  const int bh = blockIdx.y;                  // 0..383
  const int q0 = qt << 6;
  const size_t pbase = (size_t)bh * (576 * 64);

  // stage Q (hi/lo)
#pragma unroll
  for (int p = 0; p < 2; p++) {
    const int bs = ((wave << 1) + p) << 6;
    const int s = bs + lane, row = s >> 3, c = (s & 7) ^ (row & 7);
    const size_t off = pbase + (size_t)(q0 + row) * 64 + (c << 3);
    gload16(QH + off, &qh_s[bs << 3]);
    gload16(QL + off, &ql_s[bs << 3]);
  }

  int bi_q[4];
#pragma unroll
  for (int r = 0; r < 4; r++) {
    const int p = q0 + (wave << 4) + (quad << 2) + r;
    bi_q[r] = (p / 96) * 6 + ((p % 24) >> 2);
  }
  const int qmax = 6 * ((qt * 64 + 159) / 96) - 1;
  const int qmin = 6 * ((2 * qt) / 3);

  f32x4 oacc[4];
#pragma unroll
  for (int dt = 0; dt < 4; dt++) oacc[dt] = (f32x4)0.f;
  float mrun[4], lrun[4];
#pragma unroll
  for (int r = 0; r < 4; r++) { mrun[r] = -1e30f; lrun[r] = 0.f; }

#pragma unroll
  for (int kt = 0; kt < 9; ++kt) {
    const int tmink = 6 * ((2 * kt) / 3);
    const int tmaxk = 6 * ((kt * 64 + 159) / 96) - 1;
    if (tmink > qmax) continue;               // future block-tile: skip
    const bool nomask = (tmaxk <= qmin);

    drain_all();
    __syncthreads();                          // prev K/V reads done
#pragma unroll
    for (int p = 0; p < 2; p++) {
      const int bs = ((wave << 1) + p) << 6;
      const int s = bs + lane, row = s >> 3, c = (s & 7) ^ (row & 7);
      const size_t koff = pbase + (size_t)((kt << 6) + row) * 64 + (c << 3);
      gload16(KHp + koff, &kh_s[bs << 3]);
      gload16(KLp + koff, &kl_s[bs << 3]);
      const size_t voff = pbase + (size_t)row * 576 + (kt << 6) + (c << 3);
      gload16(Vp + voff, &vh_s[bs << 3]);
    }
    drain_all();                              // DMAs drained before barrier
    __syncthreads();

    // S = Q K^T  (pre-scaled by 0.125 via Q)
    f32x4 sacc[4];
#pragma unroll
    for (int j = 0; j < 4; j++) sacc[j] = (f32x4)0.f;
#pragma unroll
    for (int s2 = 0; s2 < 2; ++s2) {
      const short8 aqh = frag_read(qh_s, (wave << 4) + ln15, (s2 << 2) + quad);
      const short8 aql = frag_read(ql_s, (wave << 4) + ln15, (s2 << 2) + quad);
#pragma unroll
      for (int j = 0; j < 4; j++) {
        const short8 bkh = frag_read(kh_s, (j << 4) + ln15, (s2 << 2) + quad);
        const short8 bkl = frag_read(kl_s, (j << 4) + ln15, (s2 << 2) + quad);
        sacc[j] = __builtin_amdgcn_mfma_f32_16x16x32_bf16(aqh, bkh, sacc[j], 0, 0, 0);
        sacc[j] = __builtin_amdgcn_mfma_f32_16x16x32_bf16(aqh, bkl, sacc[j], 0, 0, 0);
        sacc[j] = __builtin_amdgcn_mfma_f32_16x16x32_bf16(aql, bkh, sacc[j], 0, 0, 0);
      }
    }

    float sv[4][4];
#pragma unroll
    for (int j = 0; j < 4; j++)
#pragma unroll
      for (int r = 0; r < 4; r++) sv[j][r] = sacc[j][r];

    if (!nomask) {
      int bi_k[4];
#pragma unroll
      for (int j = 0; j < 4; j++) {
        const int p = (kt << 6) + (j << 4) + ln15;
        bi_k[j] = (p / 96) * 6 + ((p % 24) >> 2);
      }
#pragma unroll
      for (int j = 0; j < 4; j++)
#pragma unroll
        for (int r = 0; r < 4; r++)
          if (bi_k[j] > bi_q[r]) sv[j][r] = -1e30f;
    }

    // online softmax; row r lives in the 16 lanes of this quad
#pragma unroll
    for (int r = 0; r < 4; r++) {
      float rm = fmaxf(fmaxf(sv[0][r], sv[1][r]), fmaxf(sv[2][r], sv[3][r]));
      rm = fmaxf(rm, __shfl_xor(rm, 1));
      rm = fmaxf(rm, __shfl_xor(rm, 2));
      rm = fmaxf(rm, __shfl_xor(rm, 4));
      rm = fmaxf(rm, __shfl_xor(rm, 8));
      const float mnew  = fmaxf(mrun[r], rm);
      const float alpha = __expf(mrun[r] - mnew);
      float rs = 0.f;
#pragma unroll
      for (int j = 0; j < 4; j++) {
        const float pj = __expf(sv[j][r] - mnew);
        sv[j][r] = pj; rs += pj;
      }
      rs += __shfl_xor(rs, 1);
      rs += __shfl_xor(rs, 2);
      rs += __shfl_xor(rs, 4);
      rs += __shfl_xor(rs, 8);
      lrun[r] = lrun[r] * alpha + rs;
      mrun[r] = mnew;
#pragma unroll
      for (int dt = 0; dt < 4; dt++) oacc[dt][r] *= alpha;
    }

    // P (bf16) -> own rows of p_s; wave-private, only a lgkm wait needed
#pragma unroll
    for (int j = 0; j < 4; j++)
#pragma unroll
      for (int r = 0; r < 4; r++) {
        const int row = (wave << 4) + (quad << 2) + r;
        const int col = (j << 4) + ln15;
        const int c = col >> 3, e = col & 7;
        p_s[(((row << 3) + (c ^ (row & 7))) << 3) + e] = bf16rn(sv[j][r]);
      }
    asm volatile("s_waitcnt lgkmcnt(0)" ::: "memory");

    // O += P V
#pragma unroll
    for (int s2 = 0; s2 < 2; ++s2) {
      const short8 pf = frag_read(p_s, (wave << 4) + ln15, (s2 << 2) + quad);
#pragma unroll
      for (int dt = 0; dt < 4; dt++) {
        const short8 bvh = frag_read(vh_s, (dt << 4) + ln15, (s2 << 2) + quad);
        oacc[dt] = __builtin_amdgcn_mfma_f32_16x16x32_bf16(pf, bvh, oacc[dt], 0, 0, 0);
      }
    }
  }

  // normalize + write split planes, token-major (M, C) for the proj GEMM
  const int b = bh / H_, h = bh % H_;
#pragma unroll
  for (int r = 0; r < 4; r++) {
    const float inv = 1.f / lrun[r];
    const int row_g = b * 576 + q0 + (wave << 4) + (quad << 2) + r;
#pragma unroll
    for (int dt = 0; dt < 4; dt++) {
      const float v = oacc[dt][r] * inv;
      ushort hs, ls;
      split1(v, hs, ls);
      const size_t dst = (size_t)row_g * 768 + h * 64 + (dt << 4) + ln15;
      OH[dst] = hs; OL[dst] = ls;
    }
  }
}

// ---------------------------------------------------------------------------
extern "C" void kernel_launch(void* const* d_in, const int* in_sizes, int n_in,
                              void* d_out, int out_size, void* d_ws, size_t ws_size,
                              hipStream_t stream) {
  const float* x      = (const float*)d_in[0];
  const float* qkv_w  = (const float*)d_in[1];
  const float* qkv_b  = (const float*)d_in[2];
  const float* proj_w = (const float*)d_in[3];
  const float* proj_b = (const float*)d_in[4];
  float* out = (float*)d_out;

  // ws layout (peak 205 MB < proven 226.5 MB):
  // [Qp hi/lo][Kp hi/lo][Vt] planes 0-4; [XH][XL] planes 5-6 (x split, dead
  // after QKV -> overlaid by attn-out AH/AL); [QW hi/lo 7.1MB at 7nP, dead
  // after QKV -> overlaid by PW hi/lo (split AFTER attention, round-3 order)].
  ushort* ws = (ushort*)d_ws;
  const size_t nP = (size_t)B_ * H_ * 576 * 64;   // 14,155,776 (= M_*C_)
  ushort* QpH = ws + 0 * nP;
  ushort* QpL = ws + 1 * nP;
  ushort* KpH = ws + 2 * nP;
  ushort* KpL = ws + 3 * nP;
  ushort* Vt  = ws + 4 * nP;
  ushort* XH  = ws + 5 * nP;                      // x split planes
  ushort* XL  = ws + 6 * nP;
  ushort* AH  = ws + 5 * nP;                      // attn out (overlay X planes)
  ushort* AL  = ws + 6 * nP;
  ushort* QWH = ws + 7 * nP;                      // qkv_w split
  ushort* QWL = QWH + (size_t)C3_ * C_;
  ushort* PWH = ws + 7 * nP;                      // proj_w split (overlay QW)
  ushort* PWL = PWH + (size_t)C_ * C_;

  // 1) split x and qkv_w
  split_f32<<<(M_*K_/4 + 255)/256, 256, 0, stream>>>(x, XH, XL, M_*K_/4);
  split_f32<<<(C3_*C_/4 + 255)/256, 256, 0, stream>>>(qkv_w, QWH, QWL, C3_*C_/4);

  // 2) qkv GEMM (pure DMA staging), epilogue scatters q/k/v planes
  gemm_mfma<0><<<dim3(C3_/128, M_/128), 256, 0, stream>>>(
      XH, XL, QWH, QWL, qkv_b, nullptr, QpH, QpL, KpH, KpL, Vt, C3_);

  // 3) attention (X planes now dead; writes AH/AL over them)
  attn_mfma<<<dim3(9, B_*H_), 256, 0, stream>>>(
      QpH, QpL, KpH, KpL, Vt, AH, AL);

  // 4) split proj_w (QW region dead after QKV GEMM) — round-3 order
  split_f32<<<(C_*C_/4 + 255)/256, 256, 0, stream>>>(proj_w, PWH, PWL, C_*C_/4);

  // 5) proj GEMM -> f32 out
  gemm_mfma<1><<<dim3(C_/128, M_/128), 256, 0, stream>>>(
      AH, AL, PWH, PWL, proj_b, out,
      nullptr, nullptr, nullptr, nullptr, nullptr, C_);
}